// Round 7
// baseline (272.196 us; speedup 1.0000x reference)
//
#include <hip/hip_runtime.h>

#define EMB 2048
#define UDIM 256
#define KTOT 2304
#define NE 64
#define TOPK 8
#define TPB 32               // tokens per block
#define LP 65                // reduce-slab row stride
#define SSH 6144             // shorts per k-step in wb: 3 planes * 4 nt * 64 lanes * 8

typedef __attribute__((ext_vector_type(8))) short short8;
typedef __attribute__((ext_vector_type(4))) float f32x4;

// Exact truncation 3-split: fp32 mantissa 24b = 8+8+8. x == x0+x1+x2 EXACTLY
// (bf16-truncation residuals are exactly representable; final residual has
// <= 8 significant bits so its bf16 truncation is exact).
__device__ __forceinline__ void xsplit3(float x, unsigned& s0, unsigned& s1,
                                        unsigned& s2) {
  const unsigned u = __builtin_bit_cast(unsigned, x);
  const unsigned h0 = u & 0xFFFF0000u;
  const float r1 = x - __builtin_bit_cast(float, h0);          // exact
  const unsigned u1 = __builtin_bit_cast(unsigned, r1) & 0xFFFF0000u;
  const float r2 = r1 - __builtin_bit_cast(float, u1);         // exact
  s0 = h0 >> 16;
  s1 = u1 >> 16;
  s2 = __builtin_bit_cast(unsigned, r2) >> 16;                 // exact trunc
}

// ---- prep: W fp32 [2304][64] -> exact triple-split bf16, MFMA-frag order ----
// wb[kstep][plane][nt][lane][j]:  lane = (kk>>3)*16 + (n&15), j = kk&7
// => each wave B-load is base + lane*16B: ONE coalesced dwordx4.
__global__ __launch_bounds__(256)
void prep_w(const float* __restrict__ W, unsigned short* __restrict__ wb) {
  const int flat = blockIdx.x * 256 + threadIdx.x;  // 0..147455
  const int k = flat >> 6;
  const int n = flat & 63;
  unsigned s0, s1, s2;
  xsplit3(W[flat], s0, s1, s2);  // coalesced read, exact split

  const int s = k >> 5;
  const int kk = k & 31;
  const int lane = (kk >> 3) * 16 + (n & 15);
  const int j = kk & 7;
  const int nt = n >> 4;
  const size_t base = (size_t)s * SSH + ((size_t)nt * 64 + lane) * 8 + j;
  wb[base] = (unsigned short)s0;          // plane 0
  wb[base + 2048] = (unsigned short)s1;   // plane 1
  wb[base + 4096] = (unsigned short)s2;   // plane 2
}

// ---- main: exact-split bf16 MFMA GEMM + softmax + top-8 ----
// Software-pipelined K-loop: B double-buffered 1 step ahead (sched_barrier
// pins the load cluster so the scheduler can't sink it), A 2 steps ahead.
__global__ __launch_bounds__(512, 2)
void gate_mfma(const float* __restrict__ h, const float* __restrict__ u,
               const unsigned short* __restrict__ wb,
               const float* __restrict__ b, float* __restrict__ out) {
  __shared__ float slab[TPB * LP];  // 8.3 KB

  const int tid = threadIdx.x;
  const int lane = tid & 63;
  const int wid = __builtin_amdgcn_readfirstlane(tid >> 6);
  const int tw = wid & 1;   // token tile (16 tokens)
  const int kq = wid >> 1;  // K-split slice 0..3 (576 k each)
  const int mm = lane & 15; // A: token-in-tile | B: expert-in-tile
  const int q8 = (lane >> 4) * 8;  // k-subgroup offset within frag
  const int tok0 = blockIdx.x * TPB;
  const int token = tok0 + tw * 16 + mm;

  const float* hrow = h + (size_t)token * EMB + q8;
  const float* urow = u + (size_t)token * UDIM + q8;
  const unsigned short* wlane = wb + (size_t)lane * 8;  // per-lane frag base

  f32x4 acc[4];
#pragma unroll
  for (int nt = 0; nt < 4; ++nt) acc[nt] = 0.f;

  // one GEMM segment: nsteps steps of 32 k starting at absolute k-step as0
  auto run = [&](const float* __restrict__ xp, int as0, int nsteps) {
    // prologue: A current + next, B current
    f32x4 c0 = *(const f32x4*)(xp);
    f32x4 c1 = *(const f32x4*)(xp + 4);
    f32x4 n0 = 0.f, n1 = 0.f;
    if (nsteps > 1) {
      n0 = *(const f32x4*)(xp + 32);
      n1 = *(const f32x4*)(xp + 36);
    }
    short8 Bc[12], Bn[12];
    {
      const unsigned short* ws = wlane + (size_t)as0 * SSH;
#pragma unroll
      for (int i = 0; i < 12; ++i) Bc[i] = *(const short8*)(ws + i * 512);
    }

#pragma unroll 2
    for (int s = 0; s < nsteps; ++s) {
      // issue B for step s+1 (consumed next iteration -> full-iter slack)
      if (s + 1 < nsteps) {
        const unsigned short* wn = wlane + (size_t)(as0 + s + 1) * SSH;
#pragma unroll
        for (int i = 0; i < 12; ++i) Bn[i] = *(const short8*)(wn + i * 512);
      }
      // issue A for step s+2 (2-iter slack covers L3/HBM)
      f32x4 f0 = 0.f, f1 = 0.f;
      if (s + 2 < nsteps) {
        f0 = *(const f32x4*)(xp + (s + 2) * 32);
        f1 = *(const f32x4*)(xp + (s + 2) * 32 + 4);
      }
      // pin: loads above may not sink below; compute below may not hoist
      __builtin_amdgcn_sched_barrier(0);

      // exact 3-split of current A (c was loaded 2 iterations ago)
      short8 A0, A1, A2;
#pragma unroll
      for (int j = 0; j < 8; ++j) {
        const float xv = (j < 4) ? c0[j] : c1[j - 4];
        unsigned s0, s1, s2;
        xsplit3(xv, s0, s1, s2);
        A0[j] = (short)s0;
        A1[j] = (short)s1;
        A2[j] = (short)s2;
      }
      // 4 n-tiles x 6 split terms; Bc loaded last iteration -> no stall
#pragma unroll
      for (int nt = 0; nt < 4; ++nt) {
        acc[nt] = __builtin_amdgcn_mfma_f32_16x16x32_bf16(A0, Bc[nt], acc[nt], 0, 0, 0);
        acc[nt] = __builtin_amdgcn_mfma_f32_16x16x32_bf16(A0, Bc[4 + nt], acc[nt], 0, 0, 0);
        acc[nt] = __builtin_amdgcn_mfma_f32_16x16x32_bf16(A1, Bc[nt], acc[nt], 0, 0, 0);
        acc[nt] = __builtin_amdgcn_mfma_f32_16x16x32_bf16(A1, Bc[4 + nt], acc[nt], 0, 0, 0);
        acc[nt] = __builtin_amdgcn_mfma_f32_16x16x32_bf16(A0, Bc[8 + nt], acc[nt], 0, 0, 0);
        acc[nt] = __builtin_amdgcn_mfma_f32_16x16x32_bf16(A2, Bc[nt], acc[nt], 0, 0, 0);
      }
      // rotate pipeline registers (renamed away by unroll-2)
      c0 = n0; c1 = n1; n0 = f0; n1 = f1;
#pragma unroll
      for (int i = 0; i < 12; ++i) Bc[i] = Bn[i];
    }
  };

  if (kq < 3) {
    const int kw0 = kq * 576;
    run(hrow + kw0, kw0 >> 5, 18);       // pure h: 576 k
  } else {
    run(hrow + 1728, 54, 10);            // h tail: [1728,2048)
    run(urow, 64, 8);                    // u: [2048,2304)
  }

  // ---- 4-phase K reduce into slab (D: row=token=(lane>>4)*4+reg, col=mm) ----
  const int row = tw * 16 + (lane >> 4) * 4;
  for (int ph = 0; ph < 4; ++ph) {
    if (kq == ph) {
#pragma unroll
      for (int nt = 0; nt < 4; ++nt)
#pragma unroll
        for (int r = 0; r < 4; ++r) {
          float* p = &slab[(row + r) * LP + nt * 16 + mm];
          if (ph == 0) *p = acc[nt][r]; else *p += acc[nt][r];
        }
    }
    __syncthreads();
  }

  // ---- epilogue: wave wid handles tokens [4*wid, 4*wid+4); lane = expert ----
  const float bias = b[lane];
#pragma unroll
  for (int tt = 0; tt < 4; ++tt) {
    const int t = wid * 4 + tt;
    float g = slab[t * LP + lane] + bias;

    float m = g;
#pragma unroll
    for (int off = 32; off > 0; off >>= 1)
      m = fmaxf(m, __shfl_xor(m, off));
    float pexp = __expf(g - m);
    float s = pexp;
#pragma unroll
    for (int off = 32; off > 0; off >>= 1)
      s += __shfl_xor(s, off);
    const float pn = pexp / s;

    float vv = pn;
    float topsum = 0.f;
    int sel = 0;
    for (int r = 0; r < TOPK; ++r) {
      float mv = vv;
      int mi = lane;
#pragma unroll
      for (int off = 32; off > 0; off >>= 1) {
        const float ov = __shfl_xor(mv, off);
        const int oi = __shfl_xor(mi, off);
        if (ov > mv || (ov == mv && oi < mi)) { mv = ov; mi = oi; }
      }
      topsum += mv;
      if (lane == mi) { sel = 1; vv = -1.f; }
    }

    out[(size_t)(tok0 + t) * NE + lane] =
        sel ? pn / (topsum + 1e-9f) : 0.f;
  }
}

extern "C" void kernel_launch(void* const* d_in, const int* in_sizes, int n_in,
                              void* d_out, int out_size, void* d_ws, size_t ws_size,
                              hipStream_t stream) {
  const float* h = (const float*)d_in[0];
  const float* u = (const float*)d_in[1];
  const float* W = (const float*)d_in[2];
  const float* b = (const float*)d_in[3];
  float* out = (float*)d_out;

  unsigned short* wb = (unsigned short*)d_ws;  // 72*6144 shorts = 884736 B

  const int n_tokens = in_sizes[0] / EMB;  // 16384

  hipLaunchKernelGGL(prep_w, dim3(KTOT * NE / 256), dim3(256), 0, stream, W, wb);
  hipLaunchKernelGGL(gate_mfma, dim3(n_tokens / TPB), dim3(512), 0, stream,
                     h, u, wb, b, out);
}